// Round 9
// baseline (334.357 us; speedup 1.0000x reference)
//
#include <hip/hip_runtime.h>
#include <hip/hip_bf16.h>

typedef __hip_bfloat16 bf16;

#define N_NODES 16384
#define D_FIL 512
#define D_IN 532
#define D_MODEL 1024
#define NHEAD 16
#define D_KEY 64
#define DFF 4096
#define NTREE 128
#define MEM_SLOTS 8
#define NODES_PER_TREE 128
#define EPS 1e-5f
#define XSE 544          // xs row stride in elements (bf16), 16B-aligned rows
#define XSU 272          // xs row stride in uints

__device__ inline float gelu_exact(float x) {
    return 0.5f * x * (1.0f + erff(x * 0.7071067811865476f));
}

// block-wide (256 threads) simultaneous sum of two values
__device__ inline void blockReduceSum2(float& a, float& b, float* sm) {
    int tid = threadIdx.x;
    int lane = tid & 63, wid = tid >> 6;
#pragma unroll
    for (int off = 32; off > 0; off >>= 1) {
        a += __shfl_down(a, off, 64);
        b += __shfl_down(b, off, 64);
    }
    if (lane == 0) { sm[wid] = a; sm[4 + wid] = b; }
    __syncthreads();
    if (tid == 0) {
        sm[8] = sm[0] + sm[1] + sm[2] + sm[3];
        sm[9] = sm[4] + sm[5] + sm[6] + sm[7];
    }
    __syncthreads();
    a = sm[8]; b = sm[9];
}

// ---------------- wqb[h][p] = packed bf16 pair of (q[h]·Wk[:, 2p..2p+1]) ----------------
__global__ void wq_kernel(const float* __restrict__ q, const float* __restrict__ Wk,
                          unsigned* __restrict__ wqb) {
    int h = blockIdx.x, tid = threadIdx.x;
    __shared__ float qs[64];
    if (tid < 64) qs[tid] = q[h * 64 + tid];
    __syncthreads();
    for (int p = tid; p < XSU; p += 256) {
        unsigned out = 0u;
        if (p < 266) {
            float a0 = 0.f, a1 = 0.f;
            int j0 = 2 * p;
#pragma unroll 8
            for (int d = 0; d < 64; ++d) {
                const float* wr = Wk + (size_t)(h * 64 + d) * D_IN;
                a0 += qs[d] * wr[j0];
                a1 += qs[d] * wr[j0 + 1];
            }
            unsigned u0 = (unsigned)__bfloat16_as_ushort(__float2bfloat16(a0));
            unsigned u1 = (unsigned)__bfloat16_as_ushort(__float2bfloat16(a1));
            out = (u1 << 16) | u0;
        }
        wqb[h * XSU + p] = out;
    }
}

// ---------------- wvt[j][c] = Wv[c][j]  (LDS-tiled transpose) ----------------
__global__ void transpose_wv_kernel(const float* __restrict__ Wv, float* __restrict__ wvt) {
    __shared__ float tile[32][33];
    int c0 = blockIdx.x * 32, j0 = blockIdx.y * 32;
    int tx = threadIdx.x & 31, ty = threadIdx.x >> 5;   // 32 x 8
#pragma unroll
    for (int r = 0; r < 4; ++r) {
        int cc = ty + r * 8;
        int j = j0 + tx;
        tile[cc][tx] = (j < D_IN) ? Wv[(size_t)(c0 + cc) * D_IN + j] : 0.f;
    }
    __syncthreads();
#pragma unroll
    for (int r = 0; r < 4; ++r) {
        int j = j0 + ty + r * 8;
        if (j < D_IN) wvt[(size_t)j * D_MODEL + c0 + tx] = tile[tx][ty + r * 8];
    }
}

// ------------- wave-per-node: LN(values) ++ tpd -> LN -> xs(bf16, tree-permuted, stride 544) -------------
// grid 4096 x 256: 4 waves/block, 1 node/wave. No LDS, no barriers, no qkm (separate kernel).
__global__ void node_prep_kernel(
        const float* __restrict__ values, const int* __restrict__ role,
        const int* __restrict__ bidx, const int* __restrict__ midx,
        const float* __restrict__ g_fil, const float* __restrict__ b_fil,
        const float* __restrict__ g_mha, const float* __restrict__ b_mha,
        bf16* __restrict__ xs, int* __restrict__ counts) {
    int wave = threadIdx.x >> 6;
    int l = threadIdx.x & 63;
    int n = blockIdx.x * 4 + wave;

    int row = 0;
    if (l == 0) {
        int slot = bidx[n] * MEM_SLOTS + midx[n];
        int pos = atomicAdd(&counts[slot], 1);
        row = slot * NODES_PER_TREE + pos;
    }
    row = __shfl(row, 0, 64);

    // ---- LN1 over 512 ----
    const float4* vp = (const float4*)(values + (size_t)n * D_FIL + l * 8);
    float4 v0 = vp[0], v1 = vp[1];
    float s = v0.x + v0.y + v0.z + v0.w + v1.x + v1.y + v1.z + v1.w;
    float ss = v0.x * v0.x + v0.y * v0.y + v0.z * v0.z + v0.w * v0.w
             + v1.x * v1.x + v1.y * v1.y + v1.z * v1.z + v1.w * v1.w;
#pragma unroll
    for (int m = 1; m < 64; m <<= 1) {
        s += __shfl_xor(s, m, 64);
        ss += __shfl_xor(ss, m, 64);
    }
    float mu = s * (1.f / D_FIL);
    float var = ss * (1.f / D_FIL) - mu * mu;
    float rs = rsqrtf(var + EPS);

    const float4* gf = (const float4*)(g_fil + l * 8);
    const float4* bf = (const float4*)(b_fil + l * 8);
    float4 gf0 = gf[0], gf1 = gf[1], bf0 = bf[0], bf1 = bf[1];
    float y[8];
    y[0] = (v0.x - mu) * rs * gf0.x + bf0.x;
    y[1] = (v0.y - mu) * rs * gf0.y + bf0.y;
    y[2] = (v0.z - mu) * rs * gf0.z + bf0.z;
    y[3] = (v0.w - mu) * rs * gf0.w + bf0.w;
    y[4] = (v1.x - mu) * rs * gf1.x + bf1.x;
    y[5] = (v1.y - mu) * rs * gf1.y + bf1.y;
    y[6] = (v1.z - mu) * rs * gf1.z + bf1.z;
    y[7] = (v1.w - mu) * rs * gf1.w + bf1.w;

    // ---- tpd analytic stats ----
    int r = role[n];                 // r >= 1
    int cm = 31 - __clz(r);          // highest set bit, 0..19
    float s_t = 2.f * (float)(__popc(r) - 1) - (float)cm;
    float ss_t = (float)cm;

    // ---- LN2 over 532 ----
    float s2 = y[0] + y[1] + y[2] + y[3] + y[4] + y[5] + y[6] + y[7];
    float ss2 = y[0] * y[0] + y[1] * y[1] + y[2] * y[2] + y[3] * y[3]
              + y[4] * y[4] + y[5] * y[5] + y[6] * y[6] + y[7] * y[7];
#pragma unroll
    for (int m = 1; m < 64; m <<= 1) {
        s2 += __shfl_xor(s2, m, 64);
        ss2 += __shfl_xor(ss2, m, 64);
    }
    s2 += s_t; ss2 += ss_t;
    float mu2 = s2 * (1.f / D_IN);
    float var2 = ss2 * (1.f / D_IN) - mu2 * mu2;
    float rs2 = rsqrtf(var2 + EPS);

    const float4* gm = (const float4*)(g_mha + l * 8);
    const float4* bm = (const float4*)(b_mha + l * 8);
    float4 gm0 = gm[0], gm1 = gm[1], bm0 = bm[0], bm1 = bm[1];
    float x[8];
    x[0] = (y[0] - mu2) * rs2 * gm0.x + bm0.x;
    x[1] = (y[1] - mu2) * rs2 * gm0.y + bm0.y;
    x[2] = (y[2] - mu2) * rs2 * gm0.z + bm0.z;
    x[3] = (y[3] - mu2) * rs2 * gm0.w + bm0.w;
    x[4] = (y[4] - mu2) * rs2 * gm1.x + bm1.x;
    x[5] = (y[5] - mu2) * rs2 * gm1.y + bm1.y;
    x[6] = (y[6] - mu2) * rs2 * gm1.z + bm1.z;
    x[7] = (y[7] - mu2) * rs2 * gm1.w + bm1.w;

    // one uint4 store: 8 bf16 = 16 B, rows 16B-aligned (stride 1088 B)
    {
        unsigned us[8];
#pragma unroll
        for (int k = 0; k < 8; ++k)
            us[k] = (unsigned)__bfloat16_as_ushort(__float2bfloat16(x[k]));
        uint4 pk = make_uint4((us[1] << 16) | us[0], (us[3] << 16) | us[2],
                              (us[5] << 16) | us[4], (us[7] << 16) | us[6]);
        *(uint4*)((char*)xs + (size_t)row * (XSE * 2) + 16 * l) = pk;
    }

    // tail j = 512..531, zero-pad 532..543
    if (l < 20) {
        int bit = (r >> l) & 1;
        float tpd = (l < cm) ? (bit ? 1.f : -1.f) : 0.f;
        float x2 = (tpd - mu2) * rs2 * g_mha[512 + l] + b_mha[512 + l];
        xs[(size_t)row * XSE + 512 + l] = __float2bfloat16(x2);
    } else if (l < 26) {
        ((unsigned*)xs)[(size_t)row * XSU + 266 + (l - 20)] = 0u;
    }
}

// ---------------- qkm[row][h] = xs[row] . wqb[h]  (bf16 x bf16, fp32 acc) ----------------
// grid 512 x 256: block handles 32 rows x 16 heads; thread = (head, row-pair)
__global__ __launch_bounds__(256) void qkm_kernel(const unsigned* __restrict__ xsu,
                                                  const unsigned* __restrict__ wqb,
                                                  float* __restrict__ qkmp) {
    __shared__ unsigned wshw[16 * 274];   // stride 274 words -> 16 heads on distinct banks
    int tid = threadIdx.x;
#pragma unroll
    for (int hh = 0; hh < 16; ++hh) {
        wshw[hh * 274 + tid] = wqb[hh * XSU + tid];
        if (tid < 16) wshw[hh * 274 + 256 + tid] = wqb[hh * XSU + 256 + tid];
    }
    __syncthreads();

    int h = tid & 15, rp = tid >> 4;
    int r0 = blockIdx.x * 32;
    const uint2* xr0 = (const uint2*)(xsu + (size_t)(r0 + 2 * rp) * XSU);
    const uint2* xr1 = (const uint2*)(xsu + (size_t)(r0 + 2 * rp + 1) * XSU);
    const uint2* wr  = (const uint2*)(wshw + h * 274);
    float a0 = 0.f, a1 = 0.f;
#pragma unroll 8
    for (int j = 0; j < 136; ++j) {
        uint2 wu = wr[j];
        uint2 xa = xr0[j];
        uint2 xb = xr1[j];
        float w0 = __uint_as_float(wu.x << 16), w1 = __uint_as_float(wu.x & 0xffff0000u);
        float w2 = __uint_as_float(wu.y << 16), w3 = __uint_as_float(wu.y & 0xffff0000u);
        a0 += __uint_as_float(xa.x << 16) * w0 + __uint_as_float(xa.x & 0xffff0000u) * w1
            + __uint_as_float(xa.y << 16) * w2 + __uint_as_float(xa.y & 0xffff0000u) * w3;
        a1 += __uint_as_float(xb.x << 16) * w0 + __uint_as_float(xb.x & 0xffff0000u) * w1
            + __uint_as_float(xb.y << 16) * w2 + __uint_as_float(xb.y & 0xffff0000u) * w3;
    }
    qkmp[(size_t)(r0 + 2 * rp) * NHEAD + h] = a0;
    qkmp[(size_t)(r0 + 2 * rp + 1) * NHEAD + h] = a1;
}

// ------- fused attention: softmax(4 heads) -> z in LDS -> contract onto 256 cols -------
// grid (4 head-groups, 128 trees); block 256. Head-group hg owns cols [hg*256, hg*256+256).
__global__ void attn_fused_kernel(const float* __restrict__ qkmp, const unsigned* __restrict__ xsu,
                                  const float* __restrict__ wvt, float* __restrict__ attn_out) {
    int hg = blockIdx.x, t = blockIdx.y, tid = threadIdx.x;
    __shared__ float a4[NODES_PER_TREE * 4];   // [i*4 + hh]
    __shared__ float zs[4][536];

    for (int l = tid; l < NODES_PER_TREE * 4; l += 256) {
        int i = l >> 2, hh = l & 3;
        a4[l] = qkmp[(size_t)t * NODES_PER_TREE * NHEAD + i * 16 + hg * 4 + hh] * 0.125f;
    }
    __syncthreads();

    int hh = tid >> 6, lane = tid & 63;
    {
        float s0 = a4[lane * 4 + hh], s1 = a4[(lane + 64) * 4 + hh];
        float m = fmaxf(s0, s1);
#pragma unroll
        for (int off = 32; off > 0; off >>= 1) m = fmaxf(m, __shfl_xor(m, off, 64));
        float e0 = expf(s0 - m), e1 = expf(s1 - m);
        float sum = e0 + e1;
#pragma unroll
        for (int off = 32; off > 0; off >>= 1) sum += __shfl_xor(sum, off, 64);
        float inv = 1.0f / sum;
        a4[lane * 4 + hh] = e0 * inv;
        a4[(lane + 64) * 4 + hh] = e1 * inv;
    }
    __syncthreads();

    // z[k][j] accumulation; thread owns j-pair 2*tid (+ tail)
    {
        bool hasT = tid < 10;                 // tail uints 256..265 (j = 512..531)
        float az[4][2] = {};
        float at[4][2] = {};
        const unsigned* xt = xsu + (size_t)t * NODES_PER_TREE * XSU;
        for (int i = 0; i < NODES_PER_TREE; ++i) {
            const unsigned* xr = xt + i * XSU;
            unsigned u = xr[tid];
            unsigned u2 = hasT ? xr[256 + tid] : 0u;
            float x0 = __uint_as_float(u << 16);
            float x1 = __uint_as_float(u & 0xffff0000u);
            float x2 = __uint_as_float(u2 << 16);
            float x3 = __uint_as_float(u2 & 0xffff0000u);
#pragma unroll
            for (int k = 0; k < 4; ++k) {
                float wgt = a4[i * 4 + k];
                az[k][0] += wgt * x0; az[k][1] += wgt * x1;
                at[k][0] += wgt * x2; at[k][1] += wgt * x3;
            }
        }
#pragma unroll
        for (int k = 0; k < 4; ++k) {
            *(float2*)(&zs[k][2 * tid]) = make_float2(az[k][0], az[k][1]);
            if (hasT) *(float2*)(&zs[k][512 + 2 * tid]) = make_float2(at[k][0], at[k][1]);
        }
    }
    __syncthreads();

    // contract: col c = hg*256 + tid uses head hh = tid>>6
    int c = hg * 256 + tid;
    const float* wp = wvt + c;
    float acc = 0.f;
#pragma unroll 4
    for (int j = 0; j < D_IN; ++j)
        acc += zs[hh][j] * wp[(size_t)j * D_MODEL];
    attn_out[(size_t)t * D_MODEL + c] = acc;
}

// ---------------- split-K GEMM: Cpart[split][128,N] = A[128,K-chunk] @ B[N,K-chunk]^T ----------------
// grid (N/64, splits); block 256; per-block tile 128 rows x 64 cols, K-chunk = nsb*32
__global__ void gemm_sk_kernel(const float* __restrict__ A, const float* __restrict__ B,
                               float* __restrict__ Cpart, int N, int K, int nsb) {
    __shared__ __align__(16) float As[32 * 132];
    __shared__ __align__(16) float Bs[32 * 68];
    int tid = threadIdx.x;
    int col0 = blockIdx.x * 64;
    int k0 = blockIdx.y * nsb * 32;
    float* C = Cpart + (size_t)blockIdx.y * 128 * N;

    int ty = tid >> 4, tx = tid & 15;
    int ar = tid >> 3, akk = (tid & 7) * 4;   // A staging
    int br = tid >> 2, bkk = (tid & 3) * 8;   // B staging

    float acc[8][4] = {};

    for (int s = 0; s < nsb; ++s) {
        int kb = k0 + s * 32;
#pragma unroll
        for (int p = 0; p < 4; ++p) {
            int row = ar + p * 32;
            float4 fa = *(const float4*)(A + (size_t)row * K + kb + akk);
            As[(akk + 0) * 132 + row] = fa.x;
            As[(akk + 1) * 132 + row] = fa.y;
            As[(akk + 2) * 132 + row] = fa.z;
            As[(akk + 3) * 132 + row] = fa.w;
        }
        {
            const float* bp = B + (size_t)(col0 + br) * K + kb + bkk;
            float4 f0 = *(const float4*)(bp);
            float4 f1 = *(const float4*)(bp + 4);
            Bs[(bkk + 0) * 68 + br] = f0.x; Bs[(bkk + 1) * 68 + br] = f0.y;
            Bs[(bkk + 2) * 68 + br] = f0.z; Bs[(bkk + 3) * 68 + br] = f0.w;
            Bs[(bkk + 4) * 68 + br] = f1.x; Bs[(bkk + 5) * 68 + br] = f1.y;
            Bs[(bkk + 6) * 68 + br] = f1.z; Bs[(bkk + 7) * 68 + br] = f1.w;
        }
        __syncthreads();
#pragma unroll
        for (int k = 0; k < 32; ++k) {
            float4 a0 = *(const float4*)(As + k * 132 + ty * 8);
            float4 a1 = *(const float4*)(As + k * 132 + ty * 8 + 4);
            float4 bv = *(const float4*)(Bs + k * 68 + tx * 4);
            acc[0][0] += a0.x * bv.x; acc[0][1] += a0.x * bv.y; acc[0][2] += a0.x * bv.z; acc[0][3] += a0.x * bv.w;
            acc[1][0] += a0.y * bv.x; acc[1][1] += a0.y * bv.y; acc[1][2] += a0.y * bv.z; acc[1][3] += a0.y * bv.w;
            acc[2][0] += a0.z * bv.x; acc[2][1] += a0.z * bv.y; acc[2][2] += a0.z * bv.z; acc[2][3] += a0.z * bv.w;
            acc[3][0] += a0.w * bv.x; acc[3][1] += a0.w * bv.y; acc[3][2] += a0.w * bv.z; acc[3][3] += a0.w * bv.w;
            acc[4][0] += a1.x * bv.x; acc[4][1] += a1.x * bv.y; acc[4][2] += a1.x * bv.z; acc[4][3] += a1.x * bv.w;
            acc[5][0] += a1.y * bv.x; acc[5][1] += a1.y * bv.y; acc[5][2] += a1.y * bv.z; acc[5][3] += a1.y * bv.w;
            acc[6][0] += a1.z * bv.x; acc[6][1] += a1.z * bv.y; acc[6][2] += a1.z * bv.z; acc[6][3] += a1.z * bv.w;
            acc[7][0] += a1.w * bv.x; acc[7][1] += a1.w * bv.y; acc[7][2] += a1.w * bv.z; acc[7][3] += a1.w * bv.w;
        }
        __syncthreads();
    }
#pragma unroll
    for (int r = 0; r < 8; ++r) {
        float4 v = make_float4(acc[r][0], acc[r][1], acc[r][2], acc[r][3]);
        *(float4*)(C + (size_t)(ty * 8 + r) * N + col0 + tx * 4) = v;
    }
}

// ---------------- ln_r1: reduce 8 Wo-partials + bo + qvec -> r1; LN -> l1 ----------------
__global__ void ln_r1_kernel(const float* __restrict__ po, const float* __restrict__ bo,
                             const float* __restrict__ qvec, const float* __restrict__ g,
                             const float* __restrict__ b, float* __restrict__ r1,
                             float* __restrict__ l1) {
    int t = blockIdx.x, tid = threadIdx.x;
    __shared__ float sm[16];
    float e[4];
#pragma unroll
    for (int c = 0; c < 4; ++c) {
        int j = c * 256 + tid;
        float v = bo[j] + qvec[j];
#pragma unroll
        for (int s = 0; s < 8; ++s)
            v += po[(size_t)s * NTREE * D_MODEL + (size_t)t * D_MODEL + j];
        e[c] = v;
        r1[(size_t)t * D_MODEL + j] = v;
    }
    float s = e[0] + e[1] + e[2] + e[3];
    float ss = e[0] * e[0] + e[1] * e[1] + e[2] * e[2] + e[3] * e[3];
    blockReduceSum2(s, ss, sm);
    float mu = s * (1.f / D_MODEL);
    float var = ss * (1.f / D_MODEL) - mu * mu;
    float rs = rsqrtf(var + EPS);
#pragma unroll
    for (int c = 0; c < 4; ++c) {
        int j = c * 256 + tid;
        l1[(size_t)t * D_MODEL + j] = (e[c] - mu) * rs * g[j] + b[j];
    }
}

// ---------------- gelu_reduce: h1 = gelu(sum_8 p1 + b1) ; 128x4096 elems ----------------
__global__ void gelu_reduce_kernel(const float* __restrict__ p1, const float* __restrict__ b1,
                                   float* __restrict__ h1) {
    int idx4 = (blockIdx.x * 256 + threadIdx.x) * 4;    // < 524288
    int col = idx4 & (DFF - 1);
    float4 v = *(const float4*)(b1 + col);
#pragma unroll
    for (int s = 0; s < 8; ++s) {
        float4 p = *(const float4*)(p1 + (size_t)s * NTREE * DFF + idx4);
        v.x += p.x; v.y += p.y; v.z += p.z; v.w += p.w;
    }
    v.x = gelu_exact(v.x); v.y = gelu_exact(v.y);
    v.z = gelu_exact(v.z); v.w = gelu_exact(v.w);
    *(float4*)(h1 + idx4) = v;
}

// ---------------- ln_out: reduce 16 W2-partials + b2 + r1 -> LN -> out (+zero tail) ----------------
__global__ void ln_out_kernel(const float* __restrict__ p2, const float* __restrict__ b2,
                              const float* __restrict__ r1, const float* __restrict__ g,
                              const float* __restrict__ b, float* __restrict__ out) {
    int t = blockIdx.x, tid = threadIdx.x;
    __shared__ float sm[16];
    float e[4];
#pragma unroll
    for (int c = 0; c < 4; ++c) {
        int j = c * 256 + tid;
        float v = b2[j] + r1[(size_t)t * D_MODEL + j];
#pragma unroll
        for (int s = 0; s < 16; ++s)
            v += p2[(size_t)s * NTREE * D_MODEL + (size_t)t * D_MODEL + j];
        e[c] = v;
    }
    float s = e[0] + e[1] + e[2] + e[3];
    float ss = e[0] * e[0] + e[1] * e[1] + e[2] * e[2] + e[3] * e[3];
    blockReduceSum2(s, ss, sm);
    float mu = s * (1.f / D_MODEL);
    float var = ss * (1.f / D_MODEL) - mu * mu;
    float rs = rsqrtf(var + EPS);
#pragma unroll
    for (int c = 0; c < 4; ++c) {
        int j = c * 256 + tid;
        out[(size_t)t * D_MODEL + j] = (e[c] - mu) * rs * g[j] + b[j];
    }
    if (t == 0 && tid < 128) out[(size_t)NTREE * D_MODEL + tid] = 0.f;
}

extern "C" void kernel_launch(void* const* d_in, const int* in_sizes, int n_in,
                              void* d_out, int out_size, void* d_ws, size_t ws_size,
                              hipStream_t stream) {
    const float* values = (const float*)d_in[0];
    const int* role     = (const int*)d_in[1];
    const int* bidx     = (const int*)d_in[2];
    const int* midx     = (const int*)d_in[3];
    const float* qvec   = (const float*)d_in[4];
    const float* Wk     = (const float*)d_in[5];
    const float* Wv     = (const float*)d_in[6];
    const float* Wo     = (const float*)d_in[7];
    const float* bo     = (const float*)d_in[8];
    const float* W1     = (const float*)d_in[9];
    const float* b1     = (const float*)d_in[10];
    const float* W2     = (const float*)d_in[11];
    const float* b2     = (const float*)d_in[12];
    const float* g_fil  = (const float*)d_in[13];
    const float* b_fil  = (const float*)d_in[14];
    const float* g_mha  = (const float*)d_in[15];
    const float* b_mha  = (const float*)d_in[16];
    const float* g_ff   = (const float*)d_in[17];
    const float* b_ff   = (const float*)d_in[18];
    const float* g_out  = (const float*)d_in[19];
    const float* b_out  = (const float*)d_in[20];

    // fixed region (~6.9 MB) + overlay region (~21.0 MB) = ~27.9 MB
    char* w = (char*)d_ws;
    unsigned* wqb   = (unsigned*)(w + 0);       // 16*272*4 = 17408 -> pad 18432
    float* qkmp     = (float*)(w + 18432);      // 1048576 -> 1067008
    int*   counts   = (int*)  (w + 1067008);    // 512 -> pad 1068032
    float* attn_out = (float*)(w + 1068032);    // 524288 -> 1592320
    float* r1       = (float*)(w + 1592320);    // 524288 -> 2116608
    float* l1       = (float*)(w + 2116608);    // 524288 -> 2640896
    float* h1       = (float*)(w + 2640896);    // 2097152 -> 4738048
    float* wvt      = (float*)(w + 4738048);    // 532*1024*4 = 2179072 -> 6917120
    char*  big      = w + 6917120;              // overlay region
    // phase A (attention): xs (stride 544 bf16 = 1088 B/row)
    bf16*  xs = (bf16*)big;                     // 16384*544*2 = 17825792
    // phase B (GEMMs, after attn_fused): partials overlay xs
    float* po = (float*)big;                    // 8  *128*1024*4 = 4194304
    float* p1 = (float*)(big + 4194304);        // 8  *128*4096*4 = 16777216 -> big+20971520
    float* p2 = (float*)big;                    // 16 *128*1024*4 = 8388608 (po/p1 dead by then)

    float* out = (float*)d_out;  // [128*1024] fp32 ++ [128] pad mask zeros

    hipMemsetAsync(counts, 0, 128 * sizeof(int), stream);

    wq_kernel<<<16, 256, 0, stream>>>(qvec, Wk, wqb);

    transpose_wv_kernel<<<dim3(32, 17), 256, 0, stream>>>(Wv, wvt);

    node_prep_kernel<<<N_NODES / 4, 256, 0, stream>>>(values, role, bidx, midx,
                                                      g_fil, b_fil, g_mha, b_mha,
                                                      xs, counts);

    qkm_kernel<<<N_NODES / 32, 256, 0, stream>>>((const unsigned*)xs, wqb, qkmp);

    attn_fused_kernel<<<dim3(4, NTREE), 256, 0, stream>>>(qkmp, (const unsigned*)xs, wvt, attn_out);

    // Wo: K=1024, 8 splits x (4*32=128)
    gemm_sk_kernel<<<dim3(16, 8), 256, 0, stream>>>(attn_out, Wo, po, D_MODEL, D_MODEL, 4);

    ln_r1_kernel<<<NTREE, 256, 0, stream>>>(po, bo, qvec, g_ff, b_ff, r1, l1);

    // W1: K=1024, 8 splits x 128 -> p1 [8][128][4096]
    gemm_sk_kernel<<<dim3(64, 8), 256, 0, stream>>>(l1, W1, p1, DFF, D_MODEL, 4);

    gelu_reduce_kernel<<<512, 256, 0, stream>>>(p1, b1, h1);

    // W2: K=4096, 16 splits x (8*32=256) -> p2 [16][128][1024]
    gemm_sk_kernel<<<dim3(16, 16), 256, 0, stream>>>(h1, W2, p2, D_MODEL, DFF, 8);

    ln_out_kernel<<<NTREE, 256, 0, stream>>>(p2, b2, r1, g_out, b_out, out);
}

// Round 10
// 294.640 us; speedup vs baseline: 1.1348x; 1.1348x over previous
//
#include <hip/hip_runtime.h>
#include <hip/hip_bf16.h>

typedef __hip_bfloat16 bf16;

#define N_NODES 16384
#define D_FIL 512
#define D_IN 532
#define D_MODEL 1024
#define NHEAD 16
#define D_KEY 64
#define DFF 4096
#define NTREE 128
#define MEM_SLOTS 8
#define NODES_PER_TREE 128
#define EPS 1e-5f
#define XSE 544          // xs row stride in elements (bf16), 16B-aligned rows
#define XSU 272          // xs row stride in uints

__device__ inline float gelu_exact(float x) {
    return 0.5f * x * (1.0f + erff(x * 0.7071067811865476f));
}

// block-wide (256 threads) simultaneous sum of two values
__device__ inline void blockReduceSum2(float& a, float& b, float* sm) {
    int tid = threadIdx.x;
    int lane = tid & 63, wid = tid >> 6;
#pragma unroll
    for (int off = 32; off > 0; off >>= 1) {
        a += __shfl_down(a, off, 64);
        b += __shfl_down(b, off, 64);
    }
    if (lane == 0) { sm[wid] = a; sm[4 + wid] = b; }
    __syncthreads();
    if (tid == 0) {
        sm[8] = sm[0] + sm[1] + sm[2] + sm[3];
        sm[9] = sm[4] + sm[5] + sm[6] + sm[7];
    }
    __syncthreads();
    a = sm[8]; b = sm[9];
}

// ---------------- wqb[h][p] = packed bf16 pair of (q[h]·Wk[:, 2p..2p+1]) ----------------
__global__ void wq_kernel(const float* __restrict__ q, const float* __restrict__ Wk,
                          unsigned* __restrict__ wqb) {
    int h = blockIdx.x, tid = threadIdx.x;
    __shared__ float qs[64];
    if (tid < 64) qs[tid] = q[h * 64 + tid];
    __syncthreads();
    for (int p = tid; p < XSU; p += 256) {
        unsigned out = 0u;
        if (p < 266) {
            float a0 = 0.f, a1 = 0.f;
            int j0 = 2 * p;
#pragma unroll 8
            for (int d = 0; d < 64; ++d) {
                const float* wr = Wk + (size_t)(h * 64 + d) * D_IN;
                a0 += qs[d] * wr[j0];
                a1 += qs[d] * wr[j0 + 1];
            }
            unsigned u0 = (unsigned)__bfloat16_as_ushort(__float2bfloat16(a0));
            unsigned u1 = (unsigned)__bfloat16_as_ushort(__float2bfloat16(a1));
            out = (u1 << 16) | u0;
        }
        wqb[h * XSU + p] = out;
    }
}

// ---------------- wvt[j][c] = Wv[c][j]  (LDS-tiled transpose) ----------------
__global__ void transpose_wv_kernel(const float* __restrict__ Wv, float* __restrict__ wvt) {
    __shared__ float tile[32][33];
    int c0 = blockIdx.x * 32, j0 = blockIdx.y * 32;
    int tx = threadIdx.x & 31, ty = threadIdx.x >> 5;   // 32 x 8
#pragma unroll
    for (int r = 0; r < 4; ++r) {
        int cc = ty + r * 8;
        int j = j0 + tx;
        tile[cc][tx] = (j < D_IN) ? Wv[(size_t)(c0 + cc) * D_IN + j] : 0.f;
    }
    __syncthreads();
#pragma unroll
    for (int r = 0; r < 4; ++r) {
        int j = j0 + ty + r * 8;
        if (j < D_IN) wvt[(size_t)j * D_MODEL + c0 + tx] = tile[tx][ty + r * 8];
    }
}

// ------------- wave-per-node: LN(values) ++ tpd -> LN -> xs(bf16, tree-permuted, stride 544) -------------
__global__ void node_prep_kernel(
        const float* __restrict__ values, const int* __restrict__ role,
        const int* __restrict__ bidx, const int* __restrict__ midx,
        const float* __restrict__ g_fil, const float* __restrict__ b_fil,
        const float* __restrict__ g_mha, const float* __restrict__ b_mha,
        bf16* __restrict__ xs, int* __restrict__ counts) {
    int wave = threadIdx.x >> 6;
    int l = threadIdx.x & 63;
    int n = blockIdx.x * 4 + wave;

    int row = 0;
    if (l == 0) {
        int slot = bidx[n] * MEM_SLOTS + midx[n];
        int pos = atomicAdd(&counts[slot], 1);
        row = slot * NODES_PER_TREE + pos;
    }
    row = __shfl(row, 0, 64);

    // ---- LN1 over 512 ----
    const float4* vp = (const float4*)(values + (size_t)n * D_FIL + l * 8);
    float4 v0 = vp[0], v1 = vp[1];
    float s = v0.x + v0.y + v0.z + v0.w + v1.x + v1.y + v1.z + v1.w;
    float ss = v0.x * v0.x + v0.y * v0.y + v0.z * v0.z + v0.w * v0.w
             + v1.x * v1.x + v1.y * v1.y + v1.z * v1.z + v1.w * v1.w;
#pragma unroll
    for (int m = 1; m < 64; m <<= 1) {
        s += __shfl_xor(s, m, 64);
        ss += __shfl_xor(ss, m, 64);
    }
    float mu = s * (1.f / D_FIL);
    float var = ss * (1.f / D_FIL) - mu * mu;
    float rs = rsqrtf(var + EPS);

    const float4* gf = (const float4*)(g_fil + l * 8);
    const float4* bf = (const float4*)(b_fil + l * 8);
    float4 gf0 = gf[0], gf1 = gf[1], bf0 = bf[0], bf1 = bf[1];
    float y[8];
    y[0] = (v0.x - mu) * rs * gf0.x + bf0.x;
    y[1] = (v0.y - mu) * rs * gf0.y + bf0.y;
    y[2] = (v0.z - mu) * rs * gf0.z + bf0.z;
    y[3] = (v0.w - mu) * rs * gf0.w + bf0.w;
    y[4] = (v1.x - mu) * rs * gf1.x + bf1.x;
    y[5] = (v1.y - mu) * rs * gf1.y + bf1.y;
    y[6] = (v1.z - mu) * rs * gf1.z + bf1.z;
    y[7] = (v1.w - mu) * rs * gf1.w + bf1.w;

    // ---- tpd analytic stats ----
    int r = role[n];                 // r >= 1
    int cm = 31 - __clz(r);          // highest set bit, 0..19
    float s_t = 2.f * (float)(__popc(r) - 1) - (float)cm;
    float ss_t = (float)cm;

    // ---- LN2 over 532 ----
    float s2 = y[0] + y[1] + y[2] + y[3] + y[4] + y[5] + y[6] + y[7];
    float ss2 = y[0] * y[0] + y[1] * y[1] + y[2] * y[2] + y[3] * y[3]
              + y[4] * y[4] + y[5] * y[5] + y[6] * y[6] + y[7] * y[7];
#pragma unroll
    for (int m = 1; m < 64; m <<= 1) {
        s2 += __shfl_xor(s2, m, 64);
        ss2 += __shfl_xor(ss2, m, 64);
    }
    s2 += s_t; ss2 += ss_t;
    float mu2 = s2 * (1.f / D_IN);
    float var2 = ss2 * (1.f / D_IN) - mu2 * mu2;
    float rs2 = rsqrtf(var2 + EPS);

    const float4* gm = (const float4*)(g_mha + l * 8);
    const float4* bm = (const float4*)(b_mha + l * 8);
    float4 gm0 = gm[0], gm1 = gm[1], bm0 = bm[0], bm1 = bm[1];
    float x[8];
    x[0] = (y[0] - mu2) * rs2 * gm0.x + bm0.x;
    x[1] = (y[1] - mu2) * rs2 * gm0.y + bm0.y;
    x[2] = (y[2] - mu2) * rs2 * gm0.z + bm0.z;
    x[3] = (y[3] - mu2) * rs2 * gm0.w + bm0.w;
    x[4] = (y[4] - mu2) * rs2 * gm1.x + bm1.x;
    x[5] = (y[5] - mu2) * rs2 * gm1.y + bm1.y;
    x[6] = (y[6] - mu2) * rs2 * gm1.z + bm1.z;
    x[7] = (y[7] - mu2) * rs2 * gm1.w + bm1.w;

    // one uint4 store: 8 bf16 = 16 B, rows 16B-aligned (stride 1088 B)
    {
        unsigned us[8];
#pragma unroll
        for (int k = 0; k < 8; ++k)
            us[k] = (unsigned)__bfloat16_as_ushort(__float2bfloat16(x[k]));
        uint4 pk = make_uint4((us[1] << 16) | us[0], (us[3] << 16) | us[2],
                              (us[5] << 16) | us[4], (us[7] << 16) | us[6]);
        *(uint4*)((char*)xs + (size_t)row * (XSE * 2) + 16 * l) = pk;
    }

    // tail j = 512..531, zero-pad 532..543
    if (l < 20) {
        int bit = (r >> l) & 1;
        float tpd = (l < cm) ? (bit ? 1.f : -1.f) : 0.f;
        float x2 = (tpd - mu2) * rs2 * g_mha[512 + l] + b_mha[512 + l];
        xs[(size_t)row * XSE + 512 + l] = __float2bfloat16(x2);
    } else if (l < 26) {
        ((unsigned*)xs)[(size_t)row * XSU + 266 + (l - 20)] = 0u;
    }
}

// ---------------- qkm[row][h] = xs[row] . wqb[h]  (bf16 x bf16, fp32 acc) ----------------
__global__ __launch_bounds__(256) void qkm_kernel(const unsigned* __restrict__ xsu,
                                                  const unsigned* __restrict__ wqb,
                                                  float* __restrict__ qkmp) {
    __shared__ unsigned wshw[16 * 274];   // stride 274 words -> 16 heads on distinct banks
    int tid = threadIdx.x;
#pragma unroll
    for (int hh = 0; hh < 16; ++hh) {
        wshw[hh * 274 + tid] = wqb[hh * XSU + tid];
        if (tid < 16) wshw[hh * 274 + 256 + tid] = wqb[hh * XSU + 256 + tid];
    }
    __syncthreads();

    int h = tid & 15, rp = tid >> 4;
    int r0 = blockIdx.x * 32;
    const uint2* xr0 = (const uint2*)(xsu + (size_t)(r0 + 2 * rp) * XSU);
    const uint2* xr1 = (const uint2*)(xsu + (size_t)(r0 + 2 * rp + 1) * XSU);
    const uint2* wr  = (const uint2*)(wshw + h * 274);
    float a0 = 0.f, a1 = 0.f;
#pragma unroll 8
    for (int j = 0; j < 136; ++j) {
        uint2 wu = wr[j];
        uint2 xa = xr0[j];
        uint2 xb = xr1[j];
        float w0 = __uint_as_float(wu.x << 16), w1 = __uint_as_float(wu.x & 0xffff0000u);
        float w2 = __uint_as_float(wu.y << 16), w3 = __uint_as_float(wu.y & 0xffff0000u);
        a0 += __uint_as_float(xa.x << 16) * w0 + __uint_as_float(xa.x & 0xffff0000u) * w1
            + __uint_as_float(xa.y << 16) * w2 + __uint_as_float(xa.y & 0xffff0000u) * w3;
        a1 += __uint_as_float(xb.x << 16) * w0 + __uint_as_float(xb.x & 0xffff0000u) * w1
            + __uint_as_float(xb.y << 16) * w2 + __uint_as_float(xb.y & 0xffff0000u) * w3;
    }
    qkmp[(size_t)(r0 + 2 * rp) * NHEAD + h] = a0;
    qkmp[(size_t)(r0 + 2 * rp + 1) * NHEAD + h] = a1;
}

// ------- fused attention: softmax(4 heads) -> z in LDS -> contract onto 256 cols -------
// grid (4 head-groups, 128 trees); block 256. Explicit load-batching for ILP.
__global__ void attn_fused_kernel(const float* __restrict__ qkmp, const unsigned* __restrict__ xsu,
                                  const float* __restrict__ wvt, float* __restrict__ attn_out) {
    int hg = blockIdx.x, t = blockIdx.y, tid = threadIdx.x;
    __shared__ __align__(16) float a4[NODES_PER_TREE * 4];   // [i*4 + hh]
    __shared__ float zs[4][536];

    for (int l = tid; l < NODES_PER_TREE * 4; l += 256) {
        int i = l >> 2, hh = l & 3;
        a4[l] = qkmp[(size_t)t * NODES_PER_TREE * NHEAD + i * 16 + hg * 4 + hh] * 0.125f;
    }
    __syncthreads();

    int hh = tid >> 6, lane = tid & 63;
    {
        float s0 = a4[lane * 4 + hh], s1 = a4[(lane + 64) * 4 + hh];
        float m = fmaxf(s0, s1);
#pragma unroll
        for (int off = 32; off > 0; off >>= 1) m = fmaxf(m, __shfl_xor(m, off, 64));
        float e0 = expf(s0 - m), e1 = expf(s1 - m);
        float sum = e0 + e1;
#pragma unroll
        for (int off = 32; off > 0; off >>= 1) sum += __shfl_xor(sum, off, 64);
        float inv = 1.0f / sum;
        a4[lane * 4 + hh] = e0 * inv;
        a4[(lane + 64) * 4 + hh] = e1 * inv;
    }
    __syncthreads();

    // z-phase: batches of 8 rows, explicit load arrays (8 global + 8 LDS loads in flight)
    {
        bool hasT = tid < 10;                 // tail uints 256..265 (j = 512..531)
        float az[4][2] = {};
        float at[4][2] = {};
        const unsigned* xt = xsu + (size_t)t * NODES_PER_TREE * XSU;
        for (int i0 = 0; i0 < NODES_PER_TREE; i0 += 8) {
            unsigned u[8], u2[8];
            float4 av[8];
#pragma unroll
            for (int k = 0; k < 8; ++k) u[k] = xt[(size_t)(i0 + k) * XSU + tid];
#pragma unroll
            for (int k = 0; k < 8; ++k) u2[k] = hasT ? xt[(size_t)(i0 + k) * XSU + 256 + tid] : 0u;
#pragma unroll
            for (int k = 0; k < 8; ++k) av[k] = *(const float4*)(a4 + (i0 + k) * 4);
#pragma unroll
            for (int k = 0; k < 8; ++k) {
                float x0 = __uint_as_float(u[k] << 16);
                float x1 = __uint_as_float(u[k] & 0xffff0000u);
                float x2 = __uint_as_float(u2[k] << 16);
                float x3 = __uint_as_float(u2[k] & 0xffff0000u);
                float4 a = av[k];
                az[0][0] += a.x * x0; az[0][1] += a.x * x1;
                az[1][0] += a.y * x0; az[1][1] += a.y * x1;
                az[2][0] += a.z * x0; az[2][1] += a.z * x1;
                az[3][0] += a.w * x0; az[3][1] += a.w * x1;
                at[0][0] += a.x * x2; at[0][1] += a.x * x3;
                at[1][0] += a.y * x2; at[1][1] += a.y * x3;
                at[2][0] += a.z * x2; at[2][1] += a.z * x3;
                at[3][0] += a.w * x2; at[3][1] += a.w * x3;
            }
        }
#pragma unroll
        for (int k = 0; k < 4; ++k) {
            *(float2*)(&zs[k][2 * tid]) = make_float2(az[k][0], az[k][1]);
            if (hasT) *(float2*)(&zs[k][512 + 2 * tid]) = make_float2(at[k][0], at[k][1]);
        }
    }
    __syncthreads();

    // contract: col c = hg*256 + tid; batches of 8 wvt loads, dual acc chains
    int c = hg * 256 + tid;
    const float* wp = wvt + c;
    float acc0 = 0.f, acc1 = 0.f;
    for (int j0 = 0; j0 < 528; j0 += 8) {
        float wv[8];
#pragma unroll
        for (int k = 0; k < 8; ++k) wv[k] = wp[(size_t)(j0 + k) * D_MODEL];
#pragma unroll
        for (int k = 0; k < 8; k += 2) {
            acc0 += zs[hh][j0 + k] * wv[k];
            acc1 += zs[hh][j0 + k + 1] * wv[k + 1];
        }
    }
    {
        float wv[4];
#pragma unroll
        for (int k = 0; k < 4; ++k) wv[k] = wp[(size_t)(528 + k) * D_MODEL];
#pragma unroll
        for (int k = 0; k < 4; k += 2) {
            acc0 += zs[hh][528 + k] * wv[k];
            acc1 += zs[hh][528 + k + 1] * wv[k + 1];
        }
    }
    attn_out[(size_t)t * D_MODEL + c] = acc0 + acc1;
}

// ---------------- split-K GEMM: Cpart[split][128,N] = A[128,K-chunk] @ B[N,K-chunk]^T ----------------
__global__ void gemm_sk_kernel(const float* __restrict__ A, const float* __restrict__ B,
                               float* __restrict__ Cpart, int N, int K, int nsb) {
    __shared__ __align__(16) float As[32 * 132];
    __shared__ __align__(16) float Bs[32 * 68];
    int tid = threadIdx.x;
    int col0 = blockIdx.x * 64;
    int k0 = blockIdx.y * nsb * 32;
    float* C = Cpart + (size_t)blockIdx.y * 128 * N;

    int ty = tid >> 4, tx = tid & 15;
    int ar = tid >> 3, akk = (tid & 7) * 4;   // A staging
    int br = tid >> 2, bkk = (tid & 3) * 8;   // B staging

    float acc[8][4] = {};

    for (int s = 0; s < nsb; ++s) {
        int kb = k0 + s * 32;
#pragma unroll
        for (int p = 0; p < 4; ++p) {
            int row = ar + p * 32;
            float4 fa = *(const float4*)(A + (size_t)row * K + kb + akk);
            As[(akk + 0) * 132 + row] = fa.x;
            As[(akk + 1) * 132 + row] = fa.y;
            As[(akk + 2) * 132 + row] = fa.z;
            As[(akk + 3) * 132 + row] = fa.w;
        }
        {
            const float* bp = B + (size_t)(col0 + br) * K + kb + bkk;
            float4 f0 = *(const float4*)(bp);
            float4 f1 = *(const float4*)(bp + 4);
            Bs[(bkk + 0) * 68 + br] = f0.x; Bs[(bkk + 1) * 68 + br] = f0.y;
            Bs[(bkk + 2) * 68 + br] = f0.z; Bs[(bkk + 3) * 68 + br] = f0.w;
            Bs[(bkk + 4) * 68 + br] = f1.x; Bs[(bkk + 5) * 68 + br] = f1.y;
            Bs[(bkk + 6) * 68 + br] = f1.z; Bs[(bkk + 7) * 68 + br] = f1.w;
        }
        __syncthreads();
#pragma unroll
        for (int k = 0; k < 32; ++k) {
            float4 a0 = *(const float4*)(As + k * 132 + ty * 8);
            float4 a1 = *(const float4*)(As + k * 132 + ty * 8 + 4);
            float4 bv = *(const float4*)(Bs + k * 68 + tx * 4);
            acc[0][0] += a0.x * bv.x; acc[0][1] += a0.x * bv.y; acc[0][2] += a0.x * bv.z; acc[0][3] += a0.x * bv.w;
            acc[1][0] += a0.y * bv.x; acc[1][1] += a0.y * bv.y; acc[1][2] += a0.y * bv.z; acc[1][3] += a0.y * bv.w;
            acc[2][0] += a0.z * bv.x; acc[2][1] += a0.z * bv.y; acc[2][2] += a0.z * bv.z; acc[2][3] += a0.z * bv.w;
            acc[3][0] += a0.w * bv.x; acc[3][1] += a0.w * bv.y; acc[3][2] += a0.w * bv.z; acc[3][3] += a0.w * bv.w;
            acc[4][0] += a1.x * bv.x; acc[4][1] += a1.x * bv.y; acc[4][2] += a1.x * bv.z; acc[4][3] += a1.x * bv.w;
            acc[5][0] += a1.y * bv.x; acc[5][1] += a1.y * bv.y; acc[5][2] += a1.y * bv.z; acc[5][3] += a1.y * bv.w;
            acc[6][0] += a1.z * bv.x; acc[6][1] += a1.z * bv.y; acc[6][2] += a1.z * bv.z; acc[6][3] += a1.z * bv.w;
            acc[7][0] += a1.w * bv.x; acc[7][1] += a1.w * bv.y; acc[7][2] += a1.w * bv.z; acc[7][3] += a1.w * bv.w;
        }
        __syncthreads();
    }
#pragma unroll
    for (int r = 0; r < 8; ++r) {
        float4 v = make_float4(acc[r][0], acc[r][1], acc[r][2], acc[r][3]);
        *(float4*)(C + (size_t)(ty * 8 + r) * N + col0 + tx * 4) = v;
    }
}

// ---------------- ln_r1: reduce 8 Wo-partials + bo + qvec -> r1; LN -> l1 ----------------
__global__ void ln_r1_kernel(const float* __restrict__ po, const float* __restrict__ bo,
                             const float* __restrict__ qvec, const float* __restrict__ g,
                             const float* __restrict__ b, float* __restrict__ r1,
                             float* __restrict__ l1) {
    int t = blockIdx.x, tid = threadIdx.x;
    __shared__ float sm[16];
    float e[4];
#pragma unroll
    for (int c = 0; c < 4; ++c) {
        int j = c * 256 + tid;
        float v = bo[j] + qvec[j];
#pragma unroll
        for (int s = 0; s < 8; ++s)
            v += po[(size_t)s * NTREE * D_MODEL + (size_t)t * D_MODEL + j];
        e[c] = v;
        r1[(size_t)t * D_MODEL + j] = v;
    }
    float s = e[0] + e[1] + e[2] + e[3];
    float ss = e[0] * e[0] + e[1] * e[1] + e[2] * e[2] + e[3] * e[3];
    blockReduceSum2(s, ss, sm);
    float mu = s * (1.f / D_MODEL);
    float var = ss * (1.f / D_MODEL) - mu * mu;
    float rs = rsqrtf(var + EPS);
#pragma unroll
    for (int c = 0; c < 4; ++c) {
        int j = c * 256 + tid;
        l1[(size_t)t * D_MODEL + j] = (e[c] - mu) * rs * g[j] + b[j];
    }
}

// ---------------- gelu_reduce: h1 = gelu(sum_8 p1 + b1) ; 128x4096 elems ----------------
__global__ void gelu_reduce_kernel(const float* __restrict__ p1, const float* __restrict__ b1,
                                   float* __restrict__ h1) {
    int idx4 = (blockIdx.x * 256 + threadIdx.x) * 4;    // < 524288
    int col = idx4 & (DFF - 1);
    float4 v = *(const float4*)(b1 + col);
#pragma unroll
    for (int s = 0; s < 8; ++s) {
        float4 p = *(const float4*)(p1 + (size_t)s * NTREE * DFF + idx4);
        v.x += p.x; v.y += p.y; v.z += p.z; v.w += p.w;
    }
    v.x = gelu_exact(v.x); v.y = gelu_exact(v.y);
    v.z = gelu_exact(v.z); v.w = gelu_exact(v.w);
    *(float4*)(h1 + idx4) = v;
}

// ---------------- ln_out: reduce 16 W2-partials + b2 + r1 -> LN -> out (+zero tail) ----------------
__global__ void ln_out_kernel(const float* __restrict__ p2, const float* __restrict__ b2,
                              const float* __restrict__ r1, const float* __restrict__ g,
                              const float* __restrict__ b, float* __restrict__ out) {
    int t = blockIdx.x, tid = threadIdx.x;
    __shared__ float sm[16];
    float e[4];
#pragma unroll
    for (int c = 0; c < 4; ++c) {
        int j = c * 256 + tid;
        float v = b2[j] + r1[(size_t)t * D_MODEL + j];
#pragma unroll
        for (int s = 0; s < 16; ++s)
            v += p2[(size_t)s * NTREE * D_MODEL + (size_t)t * D_MODEL + j];
        e[c] = v;
    }
    float s = e[0] + e[1] + e[2] + e[3];
    float ss = e[0] * e[0] + e[1] * e[1] + e[2] * e[2] + e[3] * e[3];
    blockReduceSum2(s, ss, sm);
    float mu = s * (1.f / D_MODEL);
    float var = ss * (1.f / D_MODEL) - mu * mu;
    float rs = rsqrtf(var + EPS);
#pragma unroll
    for (int c = 0; c < 4; ++c) {
        int j = c * 256 + tid;
        out[(size_t)t * D_MODEL + j] = (e[c] - mu) * rs * g[j] + b[j];
    }
    if (t == 0 && tid < 128) out[(size_t)NTREE * D_MODEL + tid] = 0.f;
}

extern "C" void kernel_launch(void* const* d_in, const int* in_sizes, int n_in,
                              void* d_out, int out_size, void* d_ws, size_t ws_size,
                              hipStream_t stream) {
    const float* values = (const float*)d_in[0];
    const int* role     = (const int*)d_in[1];
    const int* bidx     = (const int*)d_in[2];
    const int* midx     = (const int*)d_in[3];
    const float* qvec   = (const float*)d_in[4];
    const float* Wk     = (const float*)d_in[5];
    const float* Wv     = (const float*)d_in[6];
    const float* Wo     = (const float*)d_in[7];
    const float* bo     = (const float*)d_in[8];
    const float* W1     = (const float*)d_in[9];
    const float* b1     = (const float*)d_in[10];
    const float* W2     = (const float*)d_in[11];
    const float* b2     = (const float*)d_in[12];
    const float* g_fil  = (const float*)d_in[13];
    const float* b_fil  = (const float*)d_in[14];
    const float* g_mha  = (const float*)d_in[15];
    const float* b_mha  = (const float*)d_in[16];
    const float* g_ff   = (const float*)d_in[17];
    const float* b_ff   = (const float*)d_in[18];
    const float* g_out  = (const float*)d_in[19];
    const float* b_out  = (const float*)d_in[20];

    // fixed region (~6.9 MB) + overlay region (~21.0 MB) = ~27.9 MB
    char* w = (char*)d_ws;
    unsigned* wqb   = (unsigned*)(w + 0);       // 16*272*4 = 17408 -> pad 18432
    float* qkmp     = (float*)(w + 18432);      // 1048576 -> 1067008
    int*   counts   = (int*)  (w + 1067008);    // 512 -> pad 1068032
    float* attn_out = (float*)(w + 1068032);    // 524288 -> 1592320
    float* r1       = (float*)(w + 1592320);    // 524288 -> 2116608
    float* l1       = (float*)(w + 2116608);    // 524288 -> 2640896
    float* h1       = (float*)(w + 2640896);    // 2097152 -> 4738048
    float* wvt      = (float*)(w + 4738048);    // 532*1024*4 = 2179072 -> 6917120
    char*  big      = w + 6917120;              // overlay region
    // phase A (attention): xs (stride 544 bf16 = 1088 B/row)
    bf16*  xs = (bf16*)big;                     // 16384*544*2 = 17825792
    // phase B (GEMMs, after attn_fused): partials overlay xs
    float* po = (float*)big;                    // 8  *128*1024*4 = 4194304
    float* p1 = (float*)(big + 4194304);        // 8  *128*4096*4 = 16777216 -> big+20971520
    float* p2 = (float*)big;                    // 16 *128*1024*4 = 8388608 (po/p1 dead by then)

    float* out = (float*)d_out;  // [128*1024] fp32 ++ [128] pad mask zeros

    hipMemsetAsync(counts, 0, 128 * sizeof(int), stream);

    wq_kernel<<<16, 256, 0, stream>>>(qvec, Wk, wqb);

    transpose_wv_kernel<<<dim3(32, 17), 256, 0, stream>>>(Wv, wvt);

    node_prep_kernel<<<N_NODES / 4, 256, 0, stream>>>(values, role, bidx, midx,
                                                      g_fil, b_fil, g_mha, b_mha,
                                                      xs, counts);

    qkm_kernel<<<N_NODES / 32, 256, 0, stream>>>((const unsigned*)xs, wqb, qkmp);

    attn_fused_kernel<<<dim3(4, NTREE), 256, 0, stream>>>(qkmp, (const unsigned*)xs, wvt, attn_out);

    // Wo: K=1024, 8 splits x (4*32=128)
    gemm_sk_kernel<<<dim3(16, 8), 256, 0, stream>>>(attn_out, Wo, po, D_MODEL, D_MODEL, 4);

    ln_r1_kernel<<<NTREE, 256, 0, stream>>>(po, bo, qvec, g_ff, b_ff, r1, l1);

    // W1: K=1024, 8 splits x 128 -> p1 [8][128][4096]
    gemm_sk_kernel<<<dim3(64, 8), 256, 0, stream>>>(l1, W1, p1, DFF, D_MODEL, 4);

    gelu_reduce_kernel<<<512, 256, 0, stream>>>(p1, b1, h1);

    // W2: K=4096, 16 splits x (8*32=256) -> p2 [16][128][1024]
    gemm_sk_kernel<<<dim3(16, 16), 256, 0, stream>>>(h1, W2, p2, D_MODEL, DFF, 8);

    ln_out_kernel<<<NTREE, 256, 0, stream>>>(p2, b2, r1, g_out, b_out, out);
}